// Round 4
// baseline (2438.015 us; speedup 1.0000x reference)
//
#include <hip/hip_runtime.h>

// ---------------- types / helpers ----------------
typedef __attribute__((ext_vector_type(8))) short bf16x8;
typedef __attribute__((ext_vector_type(4))) float floatx4;
typedef unsigned long long u64;

__device__ __forceinline__ short f2bf(float f) {
  unsigned u = __float_as_uint(f);
  unsigned r = (u + 0x7fffu + ((u >> 16) & 1u)) >> 16;  // RNE
  return (short)r;
}
__device__ __forceinline__ float bf2f(short s) {
  return __uint_as_float(((unsigned)(unsigned short)s) << 16);
}

// ---- transpose + convert: W [K][N] f32 -> Wt [N][K] bf16 ----
__global__ __launch_bounds__(256) void transpose_convert(
    const float* __restrict__ W, short* __restrict__ Wt, int K, int N) {
  __shared__ float tile[32][33];
  const int nt = N >> 5;
  const int bx = blockIdx.x % nt;  // n tile
  const int by = blockIdx.x / nt;  // k tile
  const int tx = threadIdx.x & 31, ty = threadIdx.x >> 5;
#pragma unroll
  for (int i = 0; i < 32; i += 8)
    tile[ty + i][tx] = W[(size_t)(by * 32 + ty + i) * N + bx * 32 + tx];
  __syncthreads();
#pragma unroll
  for (int i = 0; i < 32; i += 8)
    Wt[(size_t)(bx * 32 + ty + i) * K + by * 32 + tx] = f2bf(tile[tx][ty + i]);
}

// ---- convert h0 f32[65536] -> bf16 row 0 of hsb ----
__global__ __launch_bounds__(256) void convert_h0(
    const float* __restrict__ h0, short* __restrict__ dst) {
  const int base = (blockIdx.x * 256 + threadIdx.x) * 4;
#pragma unroll
  for (int j = 0; j < 4; ++j) dst[base + j] = f2bf(h0[base + j]);
}

// ---- generic bf16 MFMA GEMM: C[M][N] = A[M][K] * Bt[N][K]^T + bias ----
template <int A_F32, int OUT_BF16>
__global__ __launch_bounds__(256) void gemm_kernel(
    const void* __restrict__ Aptr, const short* __restrict__ Bt,
    const float* __restrict__ bias, void* __restrict__ Cptr,
    int M, int N, int K) {
  __shared__ short As[128 * 32];
  __shared__ short Bs[128 * 32];
  const int tid = threadIdx.x;
  const int lane = tid & 63;
  const int wv = tid >> 6;
  const int wr = wv >> 1, wc = wv & 1;
  const int nb = N >> 7;
  const int m0 = (blockIdx.x / nb) * 128;
  const int n0 = (blockIdx.x % nb) * 128;
  const int m = lane & 15, q = lane >> 4;
  const int sr = tid >> 1;
  const int sh = (tid & 1) * 16;

  floatx4 acc[4][4];
#pragma unroll
  for (int i = 0; i < 4; ++i)
#pragma unroll
    for (int j = 0; j < 4; ++j) acc[i][j] = (floatx4){0.f, 0.f, 0.f, 0.f};

  for (int kt = 0; kt < K; kt += 32) {
    if (A_F32) {
      const float* A = (const float*)Aptr;
      const float* src = A + (size_t)(m0 + sr) * K + kt + sh;
      const float4 f0 = ((const float4*)src)[0];
      const float4 f1 = ((const float4*)src)[1];
      const float4 f2 = ((const float4*)src)[2];
      const float4 f3 = ((const float4*)src)[3];
      bf16x8 p0, p1;
      p0[0] = f2bf(f0.x); p0[1] = f2bf(f0.y); p0[2] = f2bf(f0.z); p0[3] = f2bf(f0.w);
      p0[4] = f2bf(f1.x); p0[5] = f2bf(f1.y); p0[6] = f2bf(f1.z); p0[7] = f2bf(f1.w);
      p1[0] = f2bf(f2.x); p1[1] = f2bf(f2.y); p1[2] = f2bf(f2.z); p1[3] = f2bf(f2.w);
      p1[4] = f2bf(f3.x); p1[5] = f2bf(f3.y); p1[6] = f2bf(f3.z); p1[7] = f2bf(f3.w);
      *(bf16x8*)&As[sr * 32 + sh] = p0;
      *(bf16x8*)&As[sr * 32 + sh + 8] = p1;
    } else {
      const short* A = (const short*)Aptr;
      const short* src = A + (size_t)(m0 + sr) * K + kt + sh;
      *(bf16x8*)&As[sr * 32 + sh] = *(const bf16x8*)src;
      *(bf16x8*)&As[sr * 32 + sh + 8] = *(const bf16x8*)(src + 8);
    }
    {
      const short* src = Bt + (size_t)(n0 + sr) * K + kt + sh;
      *(bf16x8*)&Bs[sr * 32 + sh] = *(const bf16x8*)src;
      *(bf16x8*)&Bs[sr * 32 + sh + 8] = *(const bf16x8*)(src + 8);
    }
    __syncthreads();
    bf16x8 af[4], bfr[4];
#pragma unroll
    for (int i = 0; i < 4; ++i)
      af[i] = *(bf16x8*)&As[(wr * 64 + i * 16 + m) * 32 + q * 8];
#pragma unroll
    for (int j = 0; j < 4; ++j)
      bfr[j] = *(bf16x8*)&Bs[(wc * 64 + j * 16 + m) * 32 + q * 8];
#pragma unroll
    for (int i = 0; i < 4; ++i)
#pragma unroll
      for (int j = 0; j < 4; ++j)
        acc[i][j] = __builtin_amdgcn_mfma_f32_16x16x32_bf16(af[i], bfr[j], acc[i][j], 0, 0, 0);
    __syncthreads();
  }
#pragma unroll
  for (int i = 0; i < 4; ++i) {
#pragma unroll
    for (int j = 0; j < 4; ++j) {
      const int row0 = m0 + wr * 64 + i * 16 + q * 4;
      const int col = n0 + wc * 64 + j * 16 + m;
      const float bv = bias[col];
#pragma unroll
      for (int r2 = 0; r2 < 4; ++r2) {
        const float v = acc[i][j][r2] + bv;
        if (OUT_BF16)
          ((short*)Cptr)[(size_t)(row0 + r2) * N + col] = f2bf(v);
        else
          ((float*)Cptr)[(size_t)(row0 + r2) * N + col] = v;
      }
    }
  }
}

// ---- persistent cooperative scan kernel ----
// 64 blocks x 256 threads (4 waves). block = (bt: 16 batch rows) x (ct: 64 cols).
// Each wave owns 16 cols with FULL K=1024: W_hh slice = wf[32] (128 VGPRs),
// no cross-wave reduction. hin stride 1028 shorts -> uniform LDS banks.
// Two-phase staging pipelines LLC load latency under MFMA half-1.
// Cross-block data via agent-scope atomics (LLC-coherent, no fences).
__global__ __launch_bounds__(256, 1) void scan_kernel(
    const short* __restrict__ whh_t, const short* __restrict__ xh,
    short* __restrict__ hsb, float* __restrict__ hfinal,
    unsigned* __restrict__ flags) {
  __shared__ short hin[16 * 1028];  // 16 rows x 1024 K, stride 1028
  __shared__ short hout[16 * 64];
  const int tid = threadIdx.x;
  const int lane = tid & 63;
  const int w = tid >> 6;          // wave 0..3 -> 16-col subtile
  const int bt = blockIdx.x >> 4;  // 0..3 : 16 batch rows
  const int ct = blockIdx.x & 15;  // 0..15: 64 cols
  const int m = lane & 15, q = lane >> 4;
  const int ncol = ct * 64 + w * 16 + m;

  // W_hh fragments: 16 cols x full K=1024 per wave, resident in VGPRs.
  bf16x8 wf[32];
#pragma unroll
  for (int ks = 0; ks < 32; ++ks)
    wf[ks] = *(const bf16x8*)&whh_t[(size_t)ncol * 1024 + ks * 32 + q * 8];

  unsigned* myflag = flags + blockIdx.x * 32;  // 128B stride
  const int shi = tid >> 7;          // 0/1: row parity for staging
  const int scol = (tid & 127) * 4;  // shorts within 512-wide half-row
  const int prow = tid >> 4;         // publish row (16 thr/row)
  const int pcol = (tid & 15) * 4;   // publish col

  short xv[4];
#pragma unroll
  for (int r = 0; r < 4; ++r)
    xv[r] = xh[(size_t)(bt * 16 + q * 4 + r) * 1024 + ncol];

  for (int t = 0; t < 512; ++t) {
    const short* hsrc = hsb + (size_t)t * 65536 + (size_t)bt * 16 * 1024;
    // ---- phase-1 stage: k in [0,512) ----
#pragma unroll
    for (int i = 0; i < 8; ++i) {
      const int row = i * 2 + shi;
      const u64 v = __hip_atomic_load((const u64*)(hsrc + row * 1024 + scol),
                                      __ATOMIC_RELAXED, __HIP_MEMORY_SCOPE_AGENT);
      *(u64*)&hin[row * 1028 + scol] = v;
    }
    __syncthreads();
    // ---- issue phase-2 loads; MFMA half-1 runs over their latency ----
    u64 v2[8];
#pragma unroll
    for (int i = 0; i < 8; ++i) {
      const int row = i * 2 + shi;
      v2[i] = __hip_atomic_load((const u64*)(hsrc + row * 1024 + 512 + scol),
                                __ATOMIC_RELAXED, __HIP_MEMORY_SCOPE_AGENT);
    }
    floatx4 a0 = {0.f, 0.f, 0.f, 0.f}, a1 = a0, a2 = a0, a3 = a0;
#pragma unroll
    for (int ks = 0; ks < 16; ks += 4) {
      a0 = __builtin_amdgcn_mfma_f32_16x16x32_bf16(
          *(const bf16x8*)&hin[m * 1028 + (ks + 0) * 32 + q * 8], wf[ks + 0], a0, 0, 0, 0);
      a1 = __builtin_amdgcn_mfma_f32_16x16x32_bf16(
          *(const bf16x8*)&hin[m * 1028 + (ks + 1) * 32 + q * 8], wf[ks + 1], a1, 0, 0, 0);
      a2 = __builtin_amdgcn_mfma_f32_16x16x32_bf16(
          *(const bf16x8*)&hin[m * 1028 + (ks + 2) * 32 + q * 8], wf[ks + 2], a2, 0, 0, 0);
      a3 = __builtin_amdgcn_mfma_f32_16x16x32_bf16(
          *(const bf16x8*)&hin[m * 1028 + (ks + 3) * 32 + q * 8], wf[ks + 3], a3, 0, 0, 0);
    }
#pragma unroll
    for (int i = 0; i < 8; ++i)
      *(u64*)&hin[(i * 2 + shi) * 1028 + 512 + scol] = v2[i];
    __syncthreads();
#pragma unroll
    for (int ks = 16; ks < 32; ks += 4) {
      a0 = __builtin_amdgcn_mfma_f32_16x16x32_bf16(
          *(const bf16x8*)&hin[m * 1028 + (ks + 0) * 32 + q * 8], wf[ks + 0], a0, 0, 0, 0);
      a1 = __builtin_amdgcn_mfma_f32_16x16x32_bf16(
          *(const bf16x8*)&hin[m * 1028 + (ks + 1) * 32 + q * 8], wf[ks + 1], a1, 0, 0, 0);
      a2 = __builtin_amdgcn_mfma_f32_16x16x32_bf16(
          *(const bf16x8*)&hin[m * 1028 + (ks + 2) * 32 + q * 8], wf[ks + 2], a2, 0, 0, 0);
      a3 = __builtin_amdgcn_mfma_f32_16x16x32_bf16(
          *(const bf16x8*)&hin[m * 1028 + (ks + 3) * 32 + q * 8], wf[ks + 3], a3, 0, 0, 0);
    }
    // ---- prefetch next xh during tail ----
    const int tn = (t < 511) ? t + 1 : t;
    short xn[4];
#pragma unroll
    for (int r = 0; r < 4; ++r)
      xn[r] = xh[(size_t)tn * 65536 + (size_t)(bt * 16 + q * 4 + r) * 1024 + ncol];
    // ---- tanh + hout ----
#pragma unroll
    for (int r = 0; r < 4; ++r) {
      const float s = ((a0[r] + a1[r]) + (a2[r] + a3[r])) + bf2f(xv[r]);
      const float e = __expf(2.f * s);
      const float y = 1.f - 2.f / (e + 1.f);
      hout[(q * 4 + r) * 64 + w * 16 + m] = f2bf(y);
      if (t == 511) hfinal[(size_t)(bt * 16 + q * 4 + r) * 1024 + ncol] = y;
    }
    __syncthreads();
    // ---- publish h(t+1): coalesced 8B LLC-coherent stores ----
    {
      const u64 v = *(const u64*)&hout[prow * 64 + pcol];
      __hip_atomic_store((u64*)&hsb[(size_t)(t + 1) * 65536 +
                                    (size_t)(bt * 16 + prow) * 1024 + ct * 64 + pcol],
                         v, __ATOMIC_RELAXED, __HIP_MEMORY_SCOPE_AGENT);
    }
    __syncthreads();  // s_waitcnt vmcnt(0): all publishes acked at LLC
    if (tid == 0)
      __hip_atomic_store(myflag, (unsigned)(t + 1), __ATOMIC_RELAXED,
                         __HIP_MEMORY_SCOPE_AGENT);
    // every wave polls all 64 flags (lane i -> flag i): no trailing barrier
    {
      const unsigned* fp = flags + lane * 32;
      while (true) {
        const unsigned v = __hip_atomic_load(fp, __ATOMIC_RELAXED, __HIP_MEMORY_SCOPE_AGENT);
        if (__all((int)(v > (unsigned)t))) break;
        __builtin_amdgcn_s_sleep(1);
      }
    }
#pragma unroll
    for (int r = 0; r < 4; ++r) xv[r] = xn[r];
  }
}

// ---------------- launcher ----------------
extern "C" void kernel_launch(void* const* d_in, const int* in_sizes, int n_in,
                              void* d_out, int out_size, void* d_ws, size_t ws_size,
                              hipStream_t stream) {
  (void)in_sizes; (void)n_in; (void)out_size; (void)ws_size;
  const float* inputs = (const float*)d_in[0];  // [512,64,512]
  const float* hidden = (const float*)d_in[1];  // [64,1024]
  const float* W_xh = (const float*)d_in[2];    // [512,1024]
  const float* W_hh = (const float*)d_in[3];    // [1024,1024]
  const float* b_h = (const float*)d_in[4];     // [1024]
  const float* W_hq = (const float*)d_in[5];    // [1024,512]
  const float* b_q = (const float*)d_in[6];     // [512]
  float* out = (float*)d_out;

  char* ws = (char*)d_ws;
  size_t o = 0;
  short* xh = (short*)(ws + o);    o += (size_t)512 * 64 * 1024 * 2;
  short* hsb = (short*)(ws + o);   o += (size_t)513 * 64 * 1024 * 2;
  short* wxh_t = (short*)(ws + o); o += (size_t)1024 * 512 * 2;
  short* whh_t = (short*)(ws + o); o += (size_t)1024 * 1024 * 2;
  short* whq_t = (short*)(ws + o); o += (size_t)512 * 1024 * 2;
  unsigned* flags = (unsigned*)(ws + o); o += 64 * 32 * 4;
  float* hfinal = out + (size_t)32768 * 512;

  hipMemsetAsync(flags, 0, 64 * 32 * 4, stream);
  transpose_convert<<<dim3((512 / 32) * (1024 / 32)), dim3(256), 0, stream>>>(W_xh, wxh_t, 512, 1024);
  transpose_convert<<<dim3((1024 / 32) * (1024 / 32)), dim3(256), 0, stream>>>(W_hh, whh_t, 1024, 1024);
  transpose_convert<<<dim3((1024 / 32) * (512 / 32)), dim3(256), 0, stream>>>(W_hq, whq_t, 1024, 512);
  convert_h0<<<dim3(64), dim3(256), 0, stream>>>(hidden, hsb);

  gemm_kernel<1, 1><<<dim3((32768 / 128) * (1024 / 128)), dim3(256), 0, stream>>>(
      (const void*)inputs, wxh_t, b_h, (void*)xh, 32768, 1024, 512);

  {
    void* kargs[5];
    kargs[0] = (void*)&whh_t;
    kargs[1] = (void*)&xh;
    kargs[2] = (void*)&hsb;
    kargs[3] = (void*)&hfinal;
    kargs[4] = (void*)&flags;
    hipLaunchCooperativeKernel((const void*)scan_kernel, dim3(64), dim3(256), kargs, 0, stream);
  }

  gemm_kernel<0, 0><<<dim3((32768 / 128) * (512 / 128)), dim3(256), 0, stream>>>(
      (const void*)(hsb + 65536), whq_t, b_q, (void*)out, 32768, 512, 1024);
}

// Round 5
// 1843.922 us; speedup vs baseline: 1.3222x; 1.3222x over previous
//
#include <hip/hip_runtime.h>

// ---------------- types / helpers ----------------
typedef __attribute__((ext_vector_type(8))) short bf16x8;
typedef __attribute__((ext_vector_type(4))) float floatx4;
typedef unsigned long long u64;

__device__ __forceinline__ short f2bf(float f) {
  unsigned u = __float_as_uint(f);
  unsigned r = (u + 0x7fffu + ((u >> 16) & 1u)) >> 16;  // RNE
  return (short)r;
}
__device__ __forceinline__ float bf2f(short s) {
  return __uint_as_float(((unsigned)(unsigned short)s) << 16);
}

// ---- transpose + convert: W [K][N] f32 -> Wt [N][K] bf16 ----
__global__ __launch_bounds__(256) void transpose_convert(
    const float* __restrict__ W, short* __restrict__ Wt, int K, int N) {
  __shared__ float tile[32][33];
  const int nt = N >> 5;
  const int bx = blockIdx.x % nt;  // n tile
  const int by = blockIdx.x / nt;  // k tile
  const int tx = threadIdx.x & 31, ty = threadIdx.x >> 5;
#pragma unroll
  for (int i = 0; i < 32; i += 8)
    tile[ty + i][tx] = W[(size_t)(by * 32 + ty + i) * N + bx * 32 + tx];
  __syncthreads();
#pragma unroll
  for (int i = 0; i < 32; i += 8)
    Wt[(size_t)(bx * 32 + ty + i) * K + by * 32 + tx] = f2bf(tile[tx][ty + i]);
}

// ---- convert h0 f32[65536] -> bf16 row 0 of hsb ----
__global__ __launch_bounds__(256) void convert_h0(
    const float* __restrict__ h0, short* __restrict__ dst) {
  const int base = (blockIdx.x * 256 + threadIdx.x) * 4;
#pragma unroll
  for (int j = 0; j < 4; ++j) dst[base + j] = f2bf(h0[base + j]);
}

// ---- generic bf16 MFMA GEMM: C[M][N] = A[M][K] * Bt[N][K]^T + bias ----
template <int A_F32, int OUT_BF16>
__global__ __launch_bounds__(256) void gemm_kernel(
    const void* __restrict__ Aptr, const short* __restrict__ Bt,
    const float* __restrict__ bias, void* __restrict__ Cptr,
    int M, int N, int K) {
  __shared__ short As[128 * 32];
  __shared__ short Bs[128 * 32];
  const int tid = threadIdx.x;
  const int lane = tid & 63;
  const int wv = tid >> 6;
  const int wr = wv >> 1, wc = wv & 1;
  const int nb = N >> 7;
  const int m0 = (blockIdx.x / nb) * 128;
  const int n0 = (blockIdx.x % nb) * 128;
  const int m = lane & 15, q = lane >> 4;
  const int sr = tid >> 1;
  const int sh = (tid & 1) * 16;

  floatx4 acc[4][4];
#pragma unroll
  for (int i = 0; i < 4; ++i)
#pragma unroll
    for (int j = 0; j < 4; ++j) acc[i][j] = (floatx4){0.f, 0.f, 0.f, 0.f};

  for (int kt = 0; kt < K; kt += 32) {
    if (A_F32) {
      const float* A = (const float*)Aptr;
      const float* src = A + (size_t)(m0 + sr) * K + kt + sh;
      const float4 f0 = ((const float4*)src)[0];
      const float4 f1 = ((const float4*)src)[1];
      const float4 f2 = ((const float4*)src)[2];
      const float4 f3 = ((const float4*)src)[3];
      bf16x8 p0, p1;
      p0[0] = f2bf(f0.x); p0[1] = f2bf(f0.y); p0[2] = f2bf(f0.z); p0[3] = f2bf(f0.w);
      p0[4] = f2bf(f1.x); p0[5] = f2bf(f1.y); p0[6] = f2bf(f1.z); p0[7] = f2bf(f1.w);
      p1[0] = f2bf(f2.x); p1[1] = f2bf(f2.y); p1[2] = f2bf(f2.z); p1[3] = f2bf(f2.w);
      p1[4] = f2bf(f3.x); p1[5] = f2bf(f3.y); p1[6] = f2bf(f3.z); p1[7] = f2bf(f3.w);
      *(bf16x8*)&As[sr * 32 + sh] = p0;
      *(bf16x8*)&As[sr * 32 + sh + 8] = p1;
    } else {
      const short* A = (const short*)Aptr;
      const short* src = A + (size_t)(m0 + sr) * K + kt + sh;
      *(bf16x8*)&As[sr * 32 + sh] = *(const bf16x8*)src;
      *(bf16x8*)&As[sr * 32 + sh + 8] = *(const bf16x8*)(src + 8);
    }
    {
      const short* src = Bt + (size_t)(n0 + sr) * K + kt + sh;
      *(bf16x8*)&Bs[sr * 32 + sh] = *(const bf16x8*)src;
      *(bf16x8*)&Bs[sr * 32 + sh + 8] = *(const bf16x8*)(src + 8);
    }
    __syncthreads();
    bf16x8 af[4], bfr[4];
#pragma unroll
    for (int i = 0; i < 4; ++i)
      af[i] = *(bf16x8*)&As[(wr * 64 + i * 16 + m) * 32 + q * 8];
#pragma unroll
    for (int j = 0; j < 4; ++j)
      bfr[j] = *(bf16x8*)&Bs[(wc * 64 + j * 16 + m) * 32 + q * 8];
#pragma unroll
    for (int i = 0; i < 4; ++i)
#pragma unroll
      for (int j = 0; j < 4; ++j)
        acc[i][j] = __builtin_amdgcn_mfma_f32_16x16x32_bf16(af[i], bfr[j], acc[i][j], 0, 0, 0);
    __syncthreads();
  }
#pragma unroll
  for (int i = 0; i < 4; ++i) {
#pragma unroll
    for (int j = 0; j < 4; ++j) {
      const int row0 = m0 + wr * 64 + i * 16 + q * 4;
      const int col = n0 + wc * 64 + j * 16 + m;
      const float bv = bias[col];
#pragma unroll
      for (int r2 = 0; r2 < 4; ++r2) {
        const float v = acc[i][j][r2] + bv;
        if (OUT_BF16)
          ((short*)Cptr)[(size_t)(row0 + r2) * N + col] = f2bf(v);
        else
          ((float*)Cptr)[(size_t)(row0 + r2) * N + col] = v;
      }
    }
  }
}

// ---- persistent cooperative scan kernel ----
// 64 blocks x 1024 threads (16 waves = 4 n-subtiles x 4 k-chunks).
// block = (bt: 16 batch rows) x (ct: 64 cols). wf[8] = 32 VGPRs/lane.
// hin: flat [16][1024] with 16B-granule XOR swizzle (u ^ (row&7)) ->
// conflict-free for BOTH row-contiguous stage writes and MFMA frag reads.
// Cross-block data via agent-scope atomics (LLC-coherent, no fences).
__global__ __launch_bounds__(1024) void scan_kernel(
    const short* __restrict__ whh_t, const short* __restrict__ xh,
    short* __restrict__ hsb, float* __restrict__ hfinal,
    unsigned* __restrict__ flags) {
  __shared__ short hin[16 * 1024];
  __shared__ float red[4 * 16 * 68];  // [kg][row][col pad 68]
  const int tid = threadIdx.x;
  const int lane = tid & 63;
  const int w = tid >> 6;  // wave id == staging row
  const int ns = w >> 2;   // n-subtile 0..3
  const int kg = w & 3;    // k-chunk 0..3
  const int bt = blockIdx.x >> 4;
  const int ct = blockIdx.x & 15;
  const int m = lane & 15, q = lane >> 4;
  const int ncol = ct * 64 + ns * 16 + m;

  // W_hh fragments resident in VGPRs for all 512 steps.
  bf16x8 wf[8];
#pragma unroll
  for (int ks = 0; ks < 8; ++ks)
    wf[ks] = *(const bf16x8*)&whh_t[(size_t)ncol * 1024 + kg * 256 + ks * 32 + q * 8];

  // staging: wave w stages global row bt*16+w; lane covers granules lane & lane+64
  const int sgl = lane ^ (w & 7);  // swizzled granule (low half)
  short* hinw = hin + w * 1024;
  // MFMA reads: row m, logical granule u -> hin[m*1024 + (u ^ (m&7))*8]
  const int xorm = m & 7;
  const short* hinr = hin + m * 1024;
  // publisher mapping (tid < 256): row prow, 4 cols at pc
  const int prow = tid >> 4;
  const int pc = (tid & 15) * 4;

  unsigned* myflag = flags + blockIdx.x * 32;  // 128B stride

  for (int t = 0; t < 512; ++t) {
    // ---- stage h(t) row (agent-scope loads, LLC-coherent) ----
    const short* hrow = hsb + (size_t)t * 65536 + (size_t)(bt * 16 + w) * 1024;
    const u64 a0 = __hip_atomic_load((const u64*)(hrow + lane * 8), __ATOMIC_RELAXED, __HIP_MEMORY_SCOPE_AGENT);
    const u64 a1 = __hip_atomic_load((const u64*)(hrow + lane * 8 + 4), __ATOMIC_RELAXED, __HIP_MEMORY_SCOPE_AGENT);
    const u64 a2 = __hip_atomic_load((const u64*)(hrow + 512 + lane * 8), __ATOMIC_RELAXED, __HIP_MEMORY_SCOPE_AGENT);
    const u64 a3 = __hip_atomic_load((const u64*)(hrow + 512 + lane * 8 + 4), __ATOMIC_RELAXED, __HIP_MEMORY_SCOPE_AGENT);
    // xh for this step (publishers only; plain cached load, consumed ~1us later)
    u64 xq = 0;
    if (tid < 256)
      xq = *(const u64*)(xh + (size_t)t * 65536 + (size_t)(bt * 16 + prow) * 1024 + ct * 64 + pc);
    {
      int4 v;
      v.x = (int)(unsigned)a0; v.y = (int)(a0 >> 32);
      v.z = (int)(unsigned)a1; v.w = (int)(a1 >> 32);
      *(int4*)&hinw[sgl * 8] = v;
      v.x = (int)(unsigned)a2; v.y = (int)(a2 >> 32);
      v.z = (int)(unsigned)a3; v.w = (int)(a3 >> 32);
      *(int4*)&hinw[(64 + sgl) * 8] = v;
    }
    __syncthreads();  // A: hin ready
    // ---- MFMA over this wave's k-chunk ----
    floatx4 acc = {0.f, 0.f, 0.f, 0.f};
#pragma unroll
    for (int ks = 0; ks < 8; ++ks) {
      const int u = kg * 32 + ks * 4 + q;
      const bf16x8 af = *(const bf16x8*)&hinr[(u ^ xorm) * 8];
      acc = __builtin_amdgcn_mfma_f32_16x16x32_bf16(af, wf[ks], acc, 0, 0, 0);
    }
    // partials -> red[kg][row][ns*16+m]
#pragma unroll
    for (int r2 = 0; r2 < 4; ++r2)
      red[(kg * 16 + q * 4 + r2) * 68 + ns * 16 + m] = acc[r2];
    __syncthreads();  // B: red ready
    // ---- publishers: reduce 4 k-chunks, tanh, store h(t+1) ----
    if (tid < 256) {
      const floatx4 v0 = *(const floatx4*)&red[(0 * 16 + prow) * 68 + pc];
      const floatx4 v1 = *(const floatx4*)&red[(1 * 16 + prow) * 68 + pc];
      const floatx4 v2 = *(const floatx4*)&red[(2 * 16 + prow) * 68 + pc];
      const floatx4 v3 = *(const floatx4*)&red[(3 * 16 + prow) * 68 + pc];
      const floatx4 sv = (v0 + v1) + (v2 + v3);
      u64 outv = 0;
      float yv[4];
#pragma unroll
      for (int i = 0; i < 4; ++i) {
        const float s = sv[i] + bf2f((short)(xq >> (16 * i)));
        const float e = __expf(2.f * s);
        const float y = 1.f - 2.f / (e + 1.f);
        yv[i] = y;
        outv |= (u64)(unsigned short)f2bf(y) << (16 * i);
      }
      __hip_atomic_store((u64*)&hsb[(size_t)(t + 1) * 65536 +
                                    (size_t)(bt * 16 + prow) * 1024 + ct * 64 + pc],
                         outv, __ATOMIC_RELAXED, __HIP_MEMORY_SCOPE_AGENT);
      if (t == 511)
        *(float4*)&hfinal[(size_t)(bt * 16 + prow) * 1024 + ct * 64 + pc] =
            make_float4(yv[0], yv[1], yv[2], yv[3]);
    }
    __syncthreads();  // C: publisher stores drained (vmcnt0 before barrier)
    if (tid == 0)
      __hip_atomic_store(myflag, (unsigned)(t + 1), __ATOMIC_RELAXED,
                         __HIP_MEMORY_SCOPE_AGENT);
    // every wave polls all 64 flags (lane i -> flag i); no trailing barrier
    {
      const unsigned* fp = flags + lane * 32;
      while (true) {
        const unsigned v = __hip_atomic_load(fp, __ATOMIC_RELAXED, __HIP_MEMORY_SCOPE_AGENT);
        if (__all((int)(v > (unsigned)t))) break;
        __builtin_amdgcn_s_sleep(1);
      }
    }
  }
}

// ---------------- launcher ----------------
extern "C" void kernel_launch(void* const* d_in, const int* in_sizes, int n_in,
                              void* d_out, int out_size, void* d_ws, size_t ws_size,
                              hipStream_t stream) {
  (void)in_sizes; (void)n_in; (void)out_size; (void)ws_size;
  const float* inputs = (const float*)d_in[0];  // [512,64,512]
  const float* hidden = (const float*)d_in[1];  // [64,1024]
  const float* W_xh = (const float*)d_in[2];    // [512,1024]
  const float* W_hh = (const float*)d_in[3];    // [1024,1024]
  const float* b_h = (const float*)d_in[4];     // [1024]
  const float* W_hq = (const float*)d_in[5];    // [1024,512]
  const float* b_q = (const float*)d_in[6];     // [512]
  float* out = (float*)d_out;

  char* ws = (char*)d_ws;
  size_t o = 0;
  short* xh = (short*)(ws + o);    o += (size_t)512 * 64 * 1024 * 2;
  short* hsb = (short*)(ws + o);   o += (size_t)513 * 64 * 1024 * 2;
  short* wxh_t = (short*)(ws + o); o += (size_t)1024 * 512 * 2;
  short* whh_t = (short*)(ws + o); o += (size_t)1024 * 1024 * 2;
  short* whq_t = (short*)(ws + o); o += (size_t)512 * 1024 * 2;
  unsigned* flags = (unsigned*)(ws + o); o += 64 * 32 * 4;
  float* hfinal = out + (size_t)32768 * 512;

  hipMemsetAsync(flags, 0, 64 * 32 * 4, stream);
  transpose_convert<<<dim3((512 / 32) * (1024 / 32)), dim3(256), 0, stream>>>(W_xh, wxh_t, 512, 1024);
  transpose_convert<<<dim3((1024 / 32) * (1024 / 32)), dim3(256), 0, stream>>>(W_hh, whh_t, 1024, 1024);
  transpose_convert<<<dim3((1024 / 32) * (512 / 32)), dim3(256), 0, stream>>>(W_hq, whq_t, 1024, 512);
  convert_h0<<<dim3(64), dim3(256), 0, stream>>>(hidden, hsb);

  gemm_kernel<1, 1><<<dim3((32768 / 128) * (1024 / 128)), dim3(256), 0, stream>>>(
      (const void*)inputs, wxh_t, b_h, (void*)xh, 32768, 1024, 512);

  {
    void* kargs[5];
    kargs[0] = (void*)&whh_t;
    kargs[1] = (void*)&xh;
    kargs[2] = (void*)&hsb;
    kargs[3] = (void*)&hfinal;
    kargs[4] = (void*)&flags;
    hipLaunchCooperativeKernel((const void*)scan_kernel, dim3(64), dim3(1024), kargs, 0, stream);
  }

  gemm_kernel<0, 0><<<dim3((32768 / 128) * (512 / 128)), dim3(256), 0, stream>>>(
      (const void*)(hsb + 65536), whq_t, b_q, (void*)out, 32768, 512, 1024);
}